// Round 1
// baseline (445.221 us; speedup 1.0000x reference)
//
#include <hip/hip_runtime.h>
#include <math.h>

#define HH 64
#define WW 64
#define NBATCH 4
#define NV ((HH-1)*WW)      // 4032 vertical candidates
#define NHZ (HH*(WW-1))     // 4032 horizontal candidates
#define NP (NV+NHZ)         // 8064 total candidates per image
#define EPSF 1e-3f
#define BANDF 3.0f
#define BIGF 1e10f

// ---- ws layout ----
// float4 Gpts[NBATCH][NP]          : 4*8064*16 = 516096 B
// int    NG[NBATCH]                : 16 B
// float  acc[9]                    : S[4], l1n[4], l1sum

__device__ __forceinline__ bool cand_point(const float* __restrict__ s, int p,
                                           float& pr, float& pc) {
  float v1, v2; int i, j; bool vert = (p < NV);
  if (vert) {
    i = p >> 6; j = p & 63;
    v1 = s[i*WW + j]; v2 = s[(i+1)*WW + j];
  } else {
    int q = p - NV; i = q / (WW-1); j = q - i*(WW-1);
    v1 = s[i*WW + j]; v2 = s[i*WW + j + 1];
  }
  float a1 = fabsf(v1), a2 = fabsf(v2);
  // sign(v1)*sign(v2) < 0  ==  v1*v2 < 0 whenever neither |v| <= EPS (no underflow
  // possible since |v1*v2| > 1e-6 then); the EPS terms cover the rest.
  bool valid = (v1*v2 < 0.0f) || (a1 <= EPSF) || (a2 <= EPSF);
  float a = a1 / fmaxf(a1 + a2, 1e-8f);
  a = fminf(fmaxf(a, 0.0f), 1.0f);
  pr = vert ? ((float)i + a) : (float)i;
  pc = vert ? (float)j       : ((float)j + a);
  return valid;
}

__device__ __forceinline__ void normal_at(const float* __restrict__ s, int r, int c,
                                          float& nr, float& nc) {
  float grm = (r == 0)    ? (s[WW + c] - s[c])
            : (r == HH-1) ? (s[(HH-1)*WW + c] - s[(HH-2)*WW + c])
                          : 0.5f * (s[(r+1)*WW + c] - s[(r-1)*WW + c]);
  float gcm = (c == 0)    ? (s[r*WW + 1] - s[r*WW])
            : (c == WW-1) ? (s[r*WW + WW-1] - s[r*WW + WW-2])
                          : 0.5f * (s[r*WW + c + 1] - s[r*WW + c - 1]);
  nr = grm; nc = gcm;
}

// K1: per-batch G-point compaction (order preserving) + L1 partial sum.
__global__ __launch_bounds__(256) void k_prep(const float* __restrict__ pred,
                                              const float* __restrict__ gt,
                                              float4* __restrict__ Gpts,
                                              int* __restrict__ NG,
                                              float* __restrict__ acc) {
  int b = blockIdx.x;
  const float* g  = gt   + b*HH*WW;
  const float* pr = pred + b*HH*WW;
  float4* Gb = Gpts + (size_t)b * NP;

  __shared__ int warpTot[4];
  __shared__ int baseSh;
  int tid = threadIdx.x, lane = tid & 63, wid = tid >> 6;
  if (tid == 0) baseSh = 0;
  __syncthreads();

  for (int chunk = 0; chunk < (NP + 255) / 256; ++chunk) {
    int p = chunk*256 + tid;
    bool valid = false; float r = 0.f, c = 0.f;
    if (p < NP) valid = cand_point(g, p, r, c);
    unsigned long long m = __ballot(valid ? 1 : 0);
    int pre = __popcll(m & ((1ull << lane) - 1ull));
    if (lane == 0) warpTot[wid] = __popcll(m);
    __syncthreads();
    int off = baseSh;
    for (int w2 = 0; w2 < wid; ++w2) off += warpTot[w2];
    if (valid) {
      float g2 = r*r + c*c;
      Gb[off + pre] = make_float4(r, c, g2, 0.f);
    }
    __syncthreads();
    if (tid == 0) baseSh += warpTot[0] + warpTot[1] + warpTot[2] + warpTot[3];
    __syncthreads();
  }
  if (tid == 0) NG[b] = baseSh;

  // L1 partial: sum |pred-gt| for this batch
  float loc = 0.f;
  for (int p = tid; p < HH*WW; p += 256) loc += fabsf(pr[p] - g[p]);
  for (int o = 32; o > 0; o >>= 1) loc += __shfl_down(loc, o);
  __shared__ float wsum[4];
  if (lane == 0) wsum[wid] = loc;
  __syncthreads();
  if (tid == 0) atomicAdd(&acc[8], wsum[0] + wsum[1] + wsum[2] + wsum[3]);
}

// K2: one thread per P candidate; brute-force NN over compacted valid G;
// masked accumulation of l1n and S (proj*bilin term).
__global__ __launch_bounds__(256) void k_nn(const float* __restrict__ pred,
                                            const float4* __restrict__ Gpts,
                                            const int* __restrict__ NG,
                                            float* __restrict__ acc) {
  int bb = blockIdx.x;
  int b = bb >> 5;          // 32 blocks per batch
  int chunk = bb & 31;
  int tid = threadIdx.x;
  int p = chunk*256 + tid;
  const float* s = pred + b*HH*WW;
  const float4* Gb = Gpts + (size_t)b * NP;
  int ng = NG[b];           // wave-uniform

  float contribS = 0.f, contribN = 0.f;

  float prr = 0.f, pcc = 0.f;
  bool vP = (p < NP) ? cand_point(s, p, prr, pcc) : false;

  if (vP) {
    float p2 = prr*prr + pcc*pcc;
    float bestd2 = BIGF, bestr = 0.f, bestc = 0.f;
    #pragma unroll 4
    for (int jj = 0; jj < ng; ++jj) {
      float4 gq = Gb[jj];                       // uniform address -> scalar load
      float dot = prr*gq.x + pcc*gq.y;
      float d2 = (p2 + gq.z) - 2.0f*dot;        // reference's formula/rounding
      if (d2 < bestd2) { bestd2 = d2; bestr = gq.x; bestc = gq.y; }  // first-index ties
    }
    float minP = sqrtf(fmaxf(bestd2, 0.f));
    if (minP <= BANDF) {
      int r0 = min(max((int)floorf(prr), 0), HH-1);
      int c0 = min(max((int)floorf(pcc), 0), WW-1);
      int r1 = min(r0 + 1, HH-1), c1 = min(c0 + 1, WW-1);
      float dr = prr - (float)r0, dc = pcc - (float)c0;
      float w00 = (1.f-dr)*(1.f-dc), w01 = (1.f-dr)*dc;
      float w10 = dr*(1.f-dc),       w11 = dr*dc;
      float nar, nac, nbr, nbc, ncr, ncc, ndr, ndc;
      normal_at(s, r0, c0, nar, nac);
      normal_at(s, r0, c1, nbr, nbc);
      normal_at(s, r1, c0, ncr, ncc);
      normal_at(s, r1, c1, ndr, ndc);
      float nr = w00*nar + w01*nbr + w10*ncr + w11*ndr;   // sampled raw normal (row comp)
      float nc2 = w00*nac + w01*nbc + w10*ncc + w11*ndc;  // col comp
      float bilin = w00*s[r0*WW+c0] + w01*s[r0*WW+c1]
                  + w10*s[r1*WW+c0] + w11*s[r1*WW+c1];
      float dlr = bestr - prr, dlc = bestc - pcc;          // G[idx] - P
      contribN = fabsf(nr) + fabsf(nc2);
      contribS = (dlr*nr + dlc*nc2) * bilin;
    }
  }

  // wave reduce, one atomic per wave per accumulator
  for (int o = 32; o > 0; o >>= 1) {
    contribS += __shfl_down(contribS, o);
    contribN += __shfl_down(contribN, o);
  }
  if ((tid & 63) == 0) {
    atomicAdd(&acc[b],     contribS);
    atomicAdd(&acc[4 + b], contribN);
  }
}

// K3: finalize scalar.
__global__ void k_fin(const float* __restrict__ acc, float* __restrict__ out) {
  if (threadIdx.x == 0 && blockIdx.x == 0) {
    float ps = 0.f;
    for (int b = 0; b < NBATCH; ++b) {
      ps += -(acc[b] / (acc[4 + b] + 1e-8f));   // pseudo_b ; SCALE==1, NORM_N
    }
    out[0] = ps * (1.0f / NBATCH) + acc[8] * (1.0f / (NBATCH*HH*WW));
  }
}

extern "C" void kernel_launch(void* const* d_in, const int* in_sizes, int n_in,
                              void* d_out, int out_size, void* d_ws, size_t ws_size,
                              hipStream_t stream) {
  const float* pred = (const float*)d_in[0];
  const float* gt   = (const float*)d_in[1];
  float* out = (float*)d_out;

  float4* Gpts = (float4*)d_ws;
  int*    NG   = (int*)((char*)d_ws + (size_t)NBATCH * NP * sizeof(float4));
  float*  acc  = (float*)(NG + NBATCH);   // 9 floats: S[4], l1n[4], l1sum

  hipMemsetAsync(acc, 0, 9 * sizeof(float), stream);
  k_prep<<<NBATCH, 256, 0, stream>>>(pred, gt, Gpts, NG, acc);
  k_nn<<<NBATCH * 32, 256, 0, stream>>>(pred, Gpts, NG, acc);
  k_fin<<<1, 64, 0, stream>>>(acc, out);
}

// Round 2
// 159.091 us; speedup vs baseline: 2.7985x; 2.7985x over previous
//
#include <hip/hip_runtime.h>
#include <math.h>

#define HH 64
#define WW 64
#define NB 4
#define NV ((HH-1)*WW)      // 4032 vertical candidates
#define NHZ (HH*(WW-1))     // 4032 horizontal candidates
#define NP (NV+NHZ)         // 8064 candidates per image
#define EPSF 1e-3f
#define BANDF 3.0f
#define BIGF 1e10f
#define PPB 32              // P points per k_nn block (256 thr / 8-way split)
#define NBLK_P ((NP+PPB-1)/PPB)   // 252

// ---- ws layout ----
// float2 Pp[NB][NP]   : 258048 B   (compacted valid P points, order-preserved)
// float2 Gp[NB][NP]   : 258048 B   (compacted valid G points, order-preserved)
// int    NPv[NB], NGv[NB]
// float  acc[8]       : S[4], l1n[4]   (zeroed by k_prep)
// float  accL1[NB]

__device__ __forceinline__ bool cand_point(const float* __restrict__ s, int p,
                                           float& pr, float& pc) {
  float v1, v2; int i, j; bool vert = (p < NV);
  if (vert) {
    i = p >> 6; j = p & 63;
    v1 = s[i*WW + j]; v2 = s[(i+1)*WW + j];
  } else {
    int q = p - NV; i = q / (WW-1); j = q - i*(WW-1);
    v1 = s[i*WW + j]; v2 = s[i*WW + j + 1];
  }
  float a1 = fabsf(v1), a2 = fabsf(v2);
  // sign(v1)*sign(v2) < 0 == v1*v2 < 0 when neither |v|<=EPS (no underflow then)
  bool valid = (v1*v2 < 0.0f) || (a1 <= EPSF) || (a2 <= EPSF);
  float a = a1 / fmaxf(a1 + a2, 1e-8f);
  a = fminf(fmaxf(a, 0.0f), 1.0f);
  pr = vert ? ((float)i + a) : (float)i;
  pc = vert ? (float)j       : ((float)j + a);
  return valid;
}

__device__ __forceinline__ void normal_at(const float* __restrict__ s, int r, int c,
                                          float& nr, float& nc) {
  float grm = (r == 0)    ? (s[WW + c] - s[c])
            : (r == HH-1) ? (s[(HH-1)*WW + c] - s[(HH-2)*WW + c])
                          : 0.5f * (s[(r+1)*WW + c] - s[(r-1)*WW + c]);
  float gcm = (c == 0)    ? (s[r*WW + 1] - s[r*WW])
            : (c == WW-1) ? (s[r*WW + WW-1] - s[r*WW + WW-2])
                          : 0.5f * (s[r*WW + c + 1] - s[r*WW + c - 1]);
  nr = grm; nc = gcm;
}

// K1: 8 blocks. blocks 0-3: compact gt->Gp (and zero acc). blocks 4-7:
// compact pred->Pp + L1 partial. Order-preserving 2-pass compaction,
// wave w owns contiguous range [w*2016, (w+1)*2016).
__global__ __launch_bounds__(256) void k_prep(const float* __restrict__ pred,
                                              const float* __restrict__ gt,
                                              float2* __restrict__ Pp,
                                              float2* __restrict__ Gp,
                                              int* __restrict__ NPv,
                                              int* __restrict__ NGv,
                                              float* __restrict__ acc,
                                              float* __restrict__ accL1) {
  int which = blockIdx.x >> 2;     // 0: gt, 1: pred
  int b = blockIdx.x & 3;
  const float* src = which ? (pred + b*HH*WW) : (gt + b*HH*WW);
  float2* dst = which ? (Pp + (size_t)b*NP) : (Gp + (size_t)b*NP);
  int* cnt_out = which ? NPv : NGv;

  int tid = threadIdx.x, lane = tid & 63, wid = tid >> 6;
  __shared__ int wcnt[4], wbase[4];
  const int SPAN = NP / 4;         // 2016 (not a multiple of 64 -> guard)
  int start = wid * SPAN, end = start + SPAN;

  int cnt = 0;
  for (int p0 = start; p0 < end; p0 += 64) {
    int p = p0 + lane;
    bool v = false; float r, c;
    if (p < end) v = cand_point(src, p, r, c);
    cnt += __popcll(__ballot(v ? 1 : 0));
  }
  if (lane == 0) wcnt[wid] = cnt;
  __syncthreads();
  if (tid == 0) {
    int run = 0;
    for (int w = 0; w < 4; ++w) { wbase[w] = run; run += wcnt[w]; }
    cnt_out[b] = run;
    if (!which) { acc[b] = 0.f; acc[4 + b] = 0.f; }
  }
  __syncthreads();
  int off = wbase[wid];
  for (int p0 = start; p0 < end; p0 += 64) {
    int p = p0 + lane;
    bool v = false; float r = 0.f, c = 0.f;
    if (p < end) v = cand_point(src, p, r, c);
    unsigned long long m = __ballot(v ? 1 : 0);
    if (v) dst[off + __popcll(m & ((1ull << lane) - 1ull))] = make_float2(r, c);
    off += __popcll(m);
  }

  if (which) {  // L1 partial for batch b
    const float* pr = pred + b*HH*WW;
    const float* g  = gt   + b*HH*WW;
    float loc = 0.f;
    for (int p = tid; p < HH*WW; p += 256) loc += fabsf(pr[p] - g[p]);
    for (int o = 32; o; o >>= 1) loc += __shfl_down(loc, o);
    __shared__ float ws4[4];
    if (lane == 0) ws4[wid] = loc;
    __syncthreads();
    if (tid == 0) accL1[b] = ws4[0] + ws4[1] + ws4[2] + ws4[3];
  }
}

// K2: G staged in LDS; 8-way G-split per P across lanes; butterfly argmin
// combine (first-index tie-break); masked normal/bilinear tail on lane s==0.
__global__ __launch_bounds__(256) void k_nn(const float* __restrict__ pred,
                                            const float2* __restrict__ Pp,
                                            const float2* __restrict__ Gp,
                                            const int* __restrict__ NPv,
                                            const int* __restrict__ NGv,
                                            float* __restrict__ acc) {
  int bb = blockIdx.x;
  int b = bb / NBLK_P;
  int chunk = bb - b * NBLK_P;
  int npv = NPv[b], ng = NGv[b];
  int pbase = chunk * PPB;
  if (pbase >= npv) return;            // block-uniform, before any barrier

  __shared__ float2 Gs[NP];            // 64512 B
  int tid = threadIdx.x;
  const float2* Gb = Gp + (size_t)b * NP;
  for (int i = tid; i < ng; i += 256) Gs[i] = Gb[i];
  __syncthreads();

  int s = tid & 7, grp = tid >> 3;
  int pIdx = pbase + grp;
  const float* sp = pred + b*HH*WW;
  float contribS = 0.f, contribN = 0.f;

  if (pIdx < npv) {
    float2 P = Pp[(size_t)b * NP + pIdx];
    float prr = P.x, pcc = P.y;
    float p2 = prr*prr + pcc*pcc;
    float bestd2 = BIGF, bestr = 0.f, bestc = 0.f;
    int bestj = 0x7fffffff;
    #pragma unroll 4
    for (int j = s; j < ng; j += 8) {
      float2 g = Gs[j];
      float g2 = g.x*g.x + g.y*g.y;
      float d2 = (p2 + g2) - 2.0f*(prr*g.x + pcc*g.y);   // reference's formula
      if (d2 < bestd2) { bestd2 = d2; bestr = g.x; bestc = g.y; bestj = j; }
    }
    // combine the 8 splits (lanes grp*8 .. grp*8+7); first-index tie-break
    for (int moff = 1; moff <= 4; moff <<= 1) {
      float od2 = __shfl_xor(bestd2, moff);
      float orr = __shfl_xor(bestr, moff);
      float occ = __shfl_xor(bestc, moff);
      int   oj  = __shfl_xor(bestj, moff);
      if (od2 < bestd2 || (od2 == bestd2 && oj < bestj)) {
        bestd2 = od2; bestr = orr; bestc = occ; bestj = oj;
      }
    }
    if (s == 0) {
      float minP = sqrtf(fmaxf(bestd2, 0.f));
      if (minP <= BANDF) {
        int r0 = min(max((int)floorf(prr), 0), HH-1);
        int c0 = min(max((int)floorf(pcc), 0), WW-1);
        int r1 = min(r0 + 1, HH-1), c1 = min(c0 + 1, WW-1);
        float dr = prr - (float)r0, dc = pcc - (float)c0;
        float w00 = (1.f-dr)*(1.f-dc), w01 = (1.f-dr)*dc;
        float w10 = dr*(1.f-dc),       w11 = dr*dc;
        float nar, nac, nbr, nbc, ncr, ncc, ndr, ndc;
        normal_at(sp, r0, c0, nar, nac);
        normal_at(sp, r0, c1, nbr, nbc);
        normal_at(sp, r1, c0, ncr, ncc);
        normal_at(sp, r1, c1, ndr, ndc);
        float nr  = w00*nar + w01*nbr + w10*ncr + w11*ndr;
        float nc2 = w00*nac + w01*nbc + w10*ncc + w11*ndc;
        float bilin = w00*sp[r0*WW+c0] + w01*sp[r0*WW+c1]
                    + w10*sp[r1*WW+c0] + w11*sp[r1*WW+c1];
        float dlr = bestr - prr, dlc = bestc - pcc;   // G[idx] - P
        contribN = fabsf(nr) + fabsf(nc2);
        contribS = (dlr*nr + dlc*nc2) * bilin;
      }
    }
  }

  // wave sum (nonzero only at lanes tid%8==0), then one atomic per wave
  for (int o = 8; o < 64; o <<= 1) {
    contribS += __shfl_xor(contribS, o);
    contribN += __shfl_xor(contribN, o);
  }
  if ((tid & 63) == 0) {
    atomicAdd(&acc[b],     contribS);
    atomicAdd(&acc[4 + b], contribN);
  }
}

// K3: finalize scalar.
__global__ void k_fin(const float* __restrict__ acc,
                      const float* __restrict__ accL1,
                      float* __restrict__ out) {
  if (threadIdx.x == 0 && blockIdx.x == 0) {
    float ps = 0.f, l1 = 0.f;
    for (int b = 0; b < NB; ++b) {
      ps += -(acc[b] / (acc[4 + b] + 1e-8f));   // pseudo_b (SCALE=1, NORM_N)
      l1 += accL1[b];
    }
    out[0] = ps * (1.0f / NB) + l1 * (1.0f / (NB * HH * WW));
  }
}

extern "C" void kernel_launch(void* const* d_in, const int* in_sizes, int n_in,
                              void* d_out, int out_size, void* d_ws, size_t ws_size,
                              hipStream_t stream) {
  const float* pred = (const float*)d_in[0];
  const float* gt   = (const float*)d_in[1];
  float* out = (float*)d_out;

  float2* Pp = (float2*)d_ws;
  float2* Gp = Pp + (size_t)NB * NP;
  int*    NPv = (int*)(Gp + (size_t)NB * NP);
  int*    NGv = NPv + NB;
  float*  acc = (float*)(NGv + NB);     // 8 floats: S[4], l1n[4]
  float*  accL1 = acc + 8;              // 4 floats

  k_prep<<<2 * NB, 256, 0, stream>>>(pred, gt, Pp, Gp, NPv, NGv, acc, accL1);
  k_nn<<<NB * NBLK_P, 256, 0, stream>>>(pred, Pp, Gp, NPv, NGv, acc);
  k_fin<<<1, 64, 0, stream>>>(acc, accL1, out);
}